// Round 5
// baseline (269.964 us; speedup 1.0000x reference)
//
#include <hip/hip_runtime.h>
#include <math.h>

#define KC 33            // clusters
#define ED 32            // embedding dim
#define KE (KC * ED)     // 1056
#define PAD 33           // padded leading dim for LDS tiles
#define NBLK 512         // total blocks (2/CU; LDS allows 3/CU -> co-resident)
#define BPB 64           // blocks per batch
#define TPA 128          // phase-1 points per staged tile
#define NSLOT 8          // half-waves per 256-thread block
#define TPH 256          // phase-2 points per staged tile

// ws layout (floats): sums[8*KE] | counts[8*KC] | var[8] | (int)bar[8]

__global__ void k_init(float* __restrict__ ws, int nf, int* __restrict__ bar,
                       float* __restrict__ out) {
    int i = blockIdx.x * blockDim.x + threadIdx.x;
    if (i < nf) ws[i] = 0.f;
    if (i < 8) bar[i] = 0;
    if (i == 0) out[0] = 0.f;
}

// Software grid barrier. ALL threads fence (drains each wave's outstanding
// device atomics) before arrival; spin is relaxed (no repeated L2 invalidate);
// one agent-acquire fence on exit.
__device__ __forceinline__ void grid_barrier(int* cnt, int* flag) {
    __threadfence();
    __syncthreads();
    if (threadIdx.x == 0) {
        int old = __hip_atomic_fetch_add(cnt, 1, __ATOMIC_ACQ_REL, __HIP_MEMORY_SCOPE_AGENT);
        if (old == NBLK - 1) {
            __hip_atomic_store(flag, 1, __ATOMIC_RELEASE, __HIP_MEMORY_SCOPE_AGENT);
        } else {
            while (__hip_atomic_load(flag, __ATOMIC_RELAXED, __HIP_MEMORY_SCOPE_AGENT) == 0)
                __builtin_amdgcn_s_sleep(8);
        }
    }
    __syncthreads();
    __builtin_amdgcn_fence(__ATOMIC_ACQUIRE, "agent");
}

__global__ __launch_bounds__(256) void k_fused(const float* __restrict__ emb,
                                               const int* __restrict__ lab,
                                               float* __restrict__ sums,
                                               float* __restrict__ counts,
                                               float* __restrict__ var,
                                               int* __restrict__ bar,
                                               float* __restrict__ out,
                                               int N) {
    __shared__ __align__(16) float smem[12840];   // 51.4 KB, carved per phase
    int t     = threadIdx.x;
    int b     = blockIdx.x / BPB;
    int blk   = blockIdx.x % BPB;
    int chunk = N / BPB;                           // 1024
    size_t pbase = (size_t)b * N + (size_t)blk * chunk;

    // ---------------- Phase 1: per-(b,k) sums + label histogram ----------------
    {
        float* s_tile = smem;                      // 4224 (TPA*PAD)
        float* s_priv = smem + 4224;               // 8448 (NSLOT*KE)
        int*   s_lab  = (int*)(smem + 12672);      // 128
        float* s_hist = smem + 12800;              // 33
        for (int i = t; i < NSLOT * KE; i += 256) s_priv[i] = 0.f;
        if (t < KC) s_hist[t] = 0.f;
        int e = t & 31, slot = t >> 5;
        const int NT = chunk / TPA;                // 8

        const float4* g4 = (const float4*)(emb + pbase * ED);
        float4 r0 = g4[t], r1 = g4[t + 256], r2 = g4[t + 512], r3 = g4[t + 768];
        int rl = (t < TPA) ? lab[pbase + t] : 0;
        __syncthreads();

        for (int tb = 0; tb < NT; tb++) {
            {   // unpack staged registers into padded tile
                int f, p, m;
                f = t;        p = f >> 3; m = (f & 7) * 4;
                { float* d = &s_tile[PAD * p + m]; d[0]=r0.x; d[1]=r0.y; d[2]=r0.z; d[3]=r0.w; }
                f = t + 256;  p = f >> 3; m = (f & 7) * 4;
                { float* d = &s_tile[PAD * p + m]; d[0]=r1.x; d[1]=r1.y; d[2]=r1.z; d[3]=r1.w; }
                f = t + 512;  p = f >> 3; m = (f & 7) * 4;
                { float* d = &s_tile[PAD * p + m]; d[0]=r2.x; d[1]=r2.y; d[2]=r2.z; d[3]=r2.w; }
                f = t + 768;  p = f >> 3; m = (f & 7) * 4;
                { float* d = &s_tile[PAD * p + m]; d[0]=r3.x; d[1]=r3.y; d[2]=r3.z; d[3]=r3.w; }
            }
            if (t < TPA) s_lab[t] = rl;
            __syncthreads();

            if (t < TPA) atomicAdd(&s_hist[s_lab[t]], 1.f);   // fused histogram

            if (tb + 1 < NT) {                     // prefetch next tile
                const float4* gn = (const float4*)(emb + (pbase + (size_t)(tb + 1) * TPA) * ED);
                r0 = gn[t]; r1 = gn[t + 256]; r2 = gn[t + 512]; r3 = gn[t + 768];
                if (t < TPA) rl = lab[pbase + (size_t)(tb + 1) * TPA + t];
            }

            float* priv = &s_priv[slot * KE];
#pragma unroll
            for (int st = 0; st < TPA / NSLOT; st++) {
                int pt = st * NSLOT + slot;
                float x = s_tile[pt * PAD + e];
                int   k = s_lab[pt];
                priv[k * ED + e] += x;             // private: no atomic; bank=e: free
            }
            __syncthreads();
        }

        for (int i = t; i < KE; i += 256) {
            float v = 0.f;
#pragma unroll
            for (int s = 0; s < NSLOT; s++) v += s_priv[s * KE + i];
            atomicAdd(&sums[(size_t)b * KE + i], v);
        }
        if (t < KC) atomicAdd(&counts[b * KC + t], s_hist[t]);
    }

    // prefetch phase-2 tile 0 (read-only; latency hidden by the barrier wait)
    float4 q0, q1, q2, q3, q4, q5, q6, q7; int ql;
    {
        const float4* g4 = (const float4*)(emb + pbase * ED);
        q0 = g4[t];        q1 = g4[t + 256];  q2 = g4[t + 512];  q3 = g4[t + 768];
        q4 = g4[t + 1024]; q5 = g4[t + 1280]; q6 = g4[t + 1536]; q7 = g4[t + 1792];
        ql = lab[pbase + t];
    }

    grid_barrier(bar + 0, bar + 1);

    // ---------------- Phase 2: hinge (same slice -> L2/L3-hot re-read) ----------------
    {
        float* s_tile = smem;                      // 8448 (TPH*PAD)
        float* s_ctr  = smem + 8448;               // 1089 (KC*PAD)
        float* s_inv  = smem + 9537;               // 33
        int*   s_lab  = (int*)(smem + 9570);       // 256
        float* s_red  = smem + 9826;               // 4
        float* s_cnt  = smem + 9830;               // 33
        if (t < KC) {
            float c = counts[b * KC + t];
            s_cnt[t] = fmaxf(c, 1.f);
            s_inv[t] = (t > 0 && c > 0.f) ? 1.f / fmaxf(c, 1.f) : 0.f;
        }
        __syncthreads();
        for (int i = t; i < KE; i += 256) {
            int k = i >> 5, e2 = i & 31;
            s_ctr[k * PAD + e2] = sums[(size_t)b * KE + i] / s_cnt[k];
        }

        float hs = 0.f;
        const int NT2 = chunk / TPH;               // 4
        for (int tb = 0; tb < NT2; tb++) {
            {
                int f, p, m;
                f = t;         p = f >> 3; m = (f & 7) * 4;
                { float* d = &s_tile[PAD * p + m]; d[0]=q0.x; d[1]=q0.y; d[2]=q0.z; d[3]=q0.w; }
                f = t + 256;   p = f >> 3; m = (f & 7) * 4;
                { float* d = &s_tile[PAD * p + m]; d[0]=q1.x; d[1]=q1.y; d[2]=q1.z; d[3]=q1.w; }
                f = t + 512;   p = f >> 3; m = (f & 7) * 4;
                { float* d = &s_tile[PAD * p + m]; d[0]=q2.x; d[1]=q2.y; d[2]=q2.z; d[3]=q2.w; }
                f = t + 768;   p = f >> 3; m = (f & 7) * 4;
                { float* d = &s_tile[PAD * p + m]; d[0]=q3.x; d[1]=q3.y; d[2]=q3.z; d[3]=q3.w; }
                f = t + 1024;  p = f >> 3; m = (f & 7) * 4;
                { float* d = &s_tile[PAD * p + m]; d[0]=q4.x; d[1]=q4.y; d[2]=q4.z; d[3]=q4.w; }
                f = t + 1280;  p = f >> 3; m = (f & 7) * 4;
                { float* d = &s_tile[PAD * p + m]; d[0]=q5.x; d[1]=q5.y; d[2]=q5.z; d[3]=q5.w; }
                f = t + 1536;  p = f >> 3; m = (f & 7) * 4;
                { float* d = &s_tile[PAD * p + m]; d[0]=q6.x; d[1]=q6.y; d[2]=q6.z; d[3]=q6.w; }
                f = t + 1792;  p = f >> 3; m = (f & 7) * 4;
                { float* d = &s_tile[PAD * p + m]; d[0]=q7.x; d[1]=q7.y; d[2]=q7.z; d[3]=q7.w; }
            }
            s_lab[t] = ql;
            __syncthreads();                       // also covers s_ctr writes (tb==0)

            if (tb + 1 < NT2) {
                const float4* gn = (const float4*)(emb + (pbase + (size_t)(tb + 1) * TPH) * ED);
                q0 = gn[t];        q1 = gn[t + 256];  q2 = gn[t + 512];  q3 = gn[t + 768];
                q4 = gn[t + 1024]; q5 = gn[t + 1280]; q6 = gn[t + 1536]; q7 = gn[t + 1792];
                ql = lab[pbase + (size_t)(tb + 1) * TPH + t];
            }

            int   k  = s_lab[t];
            float iv = s_inv[k];
            const float* xr = &s_tile[t * PAD];
            const float* cr = &s_ctr[k * PAD];
            float d2 = 0.f;
#pragma unroll
            for (int j = 0; j < ED; j++) {
                float d = xr[j] - cr[j];
                d2 = fmaf(d, d, d2);
            }
            float dist = sqrtf(fmaxf(d2, 1e-12f));
            hs += fmaxf(dist - 0.5f, 0.f) * iv;
            __syncthreads();
        }

        hs += __shfl_xor(hs, 1);  hs += __shfl_xor(hs, 2);  hs += __shfl_xor(hs, 4);
        hs += __shfl_xor(hs, 8);  hs += __shfl_xor(hs, 16); hs += __shfl_xor(hs, 32);
        if ((t & 63) == 0) s_red[t >> 6] = hs;
        __syncthreads();
        if (t == 0)
            atomicAdd(&var[b], s_red[0] + s_red[1] + s_red[2] + s_red[3]);
    }

    grid_barrier(bar + 2, bar + 3);

    // ---------------- Phase 3: epilogue, blocks 0..7 (one per batch) ----------------
    if (blockIdx.x < 8) {
        int fb = blockIdx.x;
        float* s_ctr = smem;                       // 1056
        float* s_cnt = smem + 1056;                // 33
        float* s_reg = smem + 1089;                // 33
        int*   s_prs = (int*)(smem + 1122);        // 33
        float* s_red = smem + 1155;                // 256

        if (t < KC) {
            float c = counts[fb * KC + t];
            s_cnt[t] = fmaxf(c, 1.f);
            s_prs[t] = (t > 0 && c > 0.f) ? 1 : 0;
        }
        __syncthreads();
        for (int i = t; i < KE; i += 256)
            s_ctr[i] = sums[(size_t)fb * KE + i] / s_cnt[i >> 5];
        __syncthreads();
        if (t < KC) {
            float n2 = 0.f;
            for (int e2 = 0; e2 < ED; e2++) { float c = s_ctr[t * ED + e2]; n2 += c * c; }
            s_reg[t] = s_prs[t] ? sqrtf(fmaxf(n2, 1e-12f)) : 0.f;
        }
        __syncthreads();

        float psum = 0.f;
        for (int q = t; q < KC * KC; q += 256) {
            int i = q / KC, j = q % KC;
            if (i < j && s_prs[i] && s_prs[j]) {
                float d2 = 0.f;
                for (int e2 = 0; e2 < ED; e2++) {
                    float d = s_ctr[i * ED + e2] - s_ctr[j * ED + e2];
                    d2 += d * d;
                }
                float cd = sqrtf(fmaxf(d2, 1e-12f));
                psum += fmaxf(3.0f - cd, 0.f);     // 2*DELTA_D = 3.0
            }
        }
        s_red[t] = psum;
        __syncthreads();
        for (int s = 128; s > 0; s >>= 1) {
            if (t < s) s_red[t] += s_red[t + s];
            __syncthreads();
        }

        if (t == 0) {
            float reg = 0.f; int n = 0;
            for (int k = 0; k < KC; k++) { reg += s_reg[k]; n += s_prs[k]; }
            float nf = (float)n;
            float variance_term = var[fb] / fmaxf(nf, 1.f);
            float npairs = nf * (nf - 1.f) * 0.5f;
            float distance_term = s_red[0] / fmaxf(npairs, 1.f);
            float reg_term = reg / fmaxf(nf, 1.f);
            float pb = variance_term + distance_term + 0.001f * reg_term;
            if (n == 0) pb = 0.f;
            atomicAdd(out, pb * 0.125f);           // / B
        }
    }
}

extern "C" void kernel_launch(void* const* d_in, const int* in_sizes, int n_in,
                              void* d_out, int out_size, void* d_ws, size_t ws_size,
                              hipStream_t stream) {
    const float* emb = (const float*)d_in[0];
    const int*   lab = (const int*)d_in[1];
    float* out = (float*)d_out;

    const int B = 8;
    const int N = in_sizes[1] / B;                 // 65536

    float* sums   = (float*)d_ws;
    float* counts = sums + (size_t)B * KE;
    float* var    = counts + (size_t)B * KC;
    int*   bar    = (int*)(var + B);

    int nf = B * KE + B * KC + B;                  // 8720
    k_init<<<(nf + 255) / 256, 256, 0, stream>>>(sums, nf, bar, out);
    k_fused<<<NBLK, 256, 0, stream>>>(emb, lab, sums, counts, var, bar, out, N);
}

// Round 6
// 195.045 us; speedup vs baseline: 1.3841x; 1.3841x over previous
//
#include <hip/hip_runtime.h>
#include <math.h>

#define KC 33            // clusters
#define ED 32            // embedding dim
#define KE (KC * ED)     // 1056
#define CPAD 33          // padded stride for LDS center/sum rows (birthday-not-64-way)
#define BPB 64           // blocks per batch
#define NPT 4            // points per thread (64*256*4*8 = 524288 pts total)

// ws layout (floats): sums[8*KE] | counts[8*KC] | var[8]

__global__ void k_init(float* __restrict__ ws, int nf, float* __restrict__ out) {
    int i = blockIdx.x * blockDim.x + threadIdx.x;
    if (i < nf) ws[i] = 0.f;
    if (i == 0) out[0] = 0.f;
}

// Pass 1: thread-owns-point scatter-add.
// Each thread: 8 float4 loads (its whole point) + 1 label load + 32 ds_add_f32
// into s_sum[k*33 + j] (birthday ~2-way banks) + 1 hist ds_add. LDS 4.5 KB,
// no syncthreads in the loop, no transpose, no shuffles.
__global__ __launch_bounds__(256) void k_accum(const float* __restrict__ emb,
                                               const int* __restrict__ lab,
                                               float* __restrict__ sums,
                                               float* __restrict__ counts,
                                               int N) {
    __shared__ float s_sum[KC * CPAD];   // 1089
    __shared__ float s_hist[KC];
    int t = threadIdx.x;
    for (int i = t; i < KC * CPAD; i += 256) s_sum[i] = 0.f;
    if (t < KC) s_hist[t] = 0.f;
    __syncthreads();

    int b   = blockIdx.x / BPB;
    int blk = blockIdx.x % BPB;
    int chunk = N / BPB;                 // 1024 = NPT*256
    size_t pbase = (size_t)b * N + (size_t)blk * chunk;
    const float4* g4 = (const float4*)(emb + pbase * ED);

    // software pipeline: load point i+1 while scattering point i
    float4 A[8], Bf[8];
    int ka, kb;
#pragma unroll
    for (int j = 0; j < 8; j++) A[j] = g4[(size_t)t * 8 + j];
    ka = lab[pbase + t];

    for (int i = 0; i < NPT; i++) {
        if (i + 1 < NPT) {
            size_t pt = (size_t)t + 256 * (i + 1);
#pragma unroll
            for (int j = 0; j < 8; j++) Bf[j] = g4[pt * 8 + j];
            kb = lab[pbase + pt];
        }
        const float* x = (const float*)A;
        float* row = &s_sum[ka * CPAD];
#pragma unroll
        for (int j = 0; j < ED; j++) atomicAdd(&row[j], x[j]);
        atomicAdd(&s_hist[ka], 1.f);
        if (i + 1 < NPT) {
#pragma unroll
            for (int j = 0; j < 8; j++) A[j] = Bf[j];
            ka = kb;
        }
    }
    __syncthreads();

    for (int i = t; i < KE; i += 256) {
        int k = i >> 5, j = i & 31;
        atomicAdd(&sums[(size_t)b * KE + i], s_sum[k * CPAD + j]);
    }
    if (t < KC) atomicAdd(&counts[b * KC + t], s_hist[t]);
}

// Pass 2: thread-owns-point hinge. Centers computed from sums/counts into LDS
// once per block; per point: 8 float4 loads + 32 fma against s_ctr[k*33+j]
// (register-resident x), sqrt+hinge per thread, one reduction per thread total.
__global__ __launch_bounds__(256) void k_hinge(const float* __restrict__ emb,
                                               const int* __restrict__ lab,
                                               const float* __restrict__ sums,
                                               const float* __restrict__ counts,
                                               float* __restrict__ var, int N) {
    __shared__ float s_ctr[KC * CPAD];   // 1089
    __shared__ float s_inv[KC];
    __shared__ float s_red[4];
    int t = threadIdx.x;
    int b   = blockIdx.x / BPB;
    int blk = blockIdx.x % BPB;
    int chunk = N / BPB;
    size_t pbase = (size_t)b * N + (size_t)blk * chunk;
    const float4* g4 = (const float4*)(emb + pbase * ED);

    if (t < KC) {
        float c = counts[b * KC + t];
        s_inv[t] = (t > 0 && c > 0.f) ? 1.f / fmaxf(c, 1.f) : 0.f;
    }
    for (int i = t; i < KE; i += 256) {
        int k = i >> 5, j = i & 31;
        s_ctr[k * CPAD + j] = sums[(size_t)b * KE + i] / fmaxf(counts[b * KC + k], 1.f);
    }
    __syncthreads();

    float4 A[8], Bf[8];
    int ka, kb;
#pragma unroll
    for (int j = 0; j < 8; j++) A[j] = g4[(size_t)t * 8 + j];
    ka = lab[pbase + t];

    float hs = 0.f;
    for (int i = 0; i < NPT; i++) {
        if (i + 1 < NPT) {
            size_t pt = (size_t)t + 256 * (i + 1);
#pragma unroll
            for (int j = 0; j < 8; j++) Bf[j] = g4[pt * 8 + j];
            kb = lab[pbase + pt];
        }
        const float* x = (const float*)A;
        const float* cr = &s_ctr[ka * CPAD];
        float d2 = 0.f;
#pragma unroll
        for (int j = 0; j < ED; j++) {
            float d = x[j] - cr[j];
            d2 = fmaf(d, d, d2);
        }
        float dist = sqrtf(fmaxf(d2, 1e-12f));
        hs += fmaxf(dist - 0.5f, 0.f) * s_inv[ka];
        if (i + 1 < NPT) {
#pragma unroll
            for (int j = 0; j < 8; j++) A[j] = Bf[j];
            ka = kb;
        }
    }

    // one reduction per thread for the whole kernel
    hs += __shfl_xor(hs, 1);  hs += __shfl_xor(hs, 2);  hs += __shfl_xor(hs, 4);
    hs += __shfl_xor(hs, 8);  hs += __shfl_xor(hs, 16); hs += __shfl_xor(hs, 32);
    if ((t & 63) == 0) s_red[t >> 6] = hs;
    __syncthreads();
    if (t == 0)
        atomicAdd(&var[b], s_red[0] + s_red[1] + s_red[2] + s_red[3]);
}

// Epilogue: one block per batch; recompute centers from sums/counts.
__global__ __launch_bounds__(256) void k_final(const float* __restrict__ sums,
                                               const float* __restrict__ counts,
                                               const float* __restrict__ var,
                                               float* __restrict__ out, int B) {
    __shared__ float s_ctr[KE];
    __shared__ float s_cnt[KC];
    __shared__ float s_reg[KC];
    __shared__ int   s_prs[KC];
    __shared__ float s_red[256];
    int b = blockIdx.x;
    int t = threadIdx.x;

    if (t < KC) {
        float c = counts[b * KC + t];
        s_cnt[t] = fmaxf(c, 1.f);
        s_prs[t] = (t > 0 && c > 0.f) ? 1 : 0;
    }
    __syncthreads();
    for (int i = t; i < KE; i += 256)
        s_ctr[i] = sums[(size_t)b * KE + i] / s_cnt[i >> 5];
    __syncthreads();
    if (t < KC) {
        float n2 = 0.f;
        for (int e2 = 0; e2 < ED; e2++) { float c = s_ctr[t * ED + e2]; n2 += c * c; }
        s_reg[t] = s_prs[t] ? sqrtf(fmaxf(n2, 1e-12f)) : 0.f;
    }
    __syncthreads();

    float psum = 0.f;
    for (int q = t; q < KC * KC; q += 256) {
        int i = q / KC, j = q % KC;
        if (i < j && s_prs[i] && s_prs[j]) {
            float d2 = 0.f;
            for (int e2 = 0; e2 < ED; e2++) {
                float d = s_ctr[i * ED + e2] - s_ctr[j * ED + e2];
                d2 += d * d;
            }
            float cd = sqrtf(fmaxf(d2, 1e-12f));
            psum += fmaxf(3.0f - cd, 0.f);     // 2*DELTA_D = 3.0
        }
    }
    s_red[t] = psum;
    __syncthreads();
    for (int s = 128; s > 0; s >>= 1) {
        if (t < s) s_red[t] += s_red[t + s];
        __syncthreads();
    }

    if (t == 0) {
        float reg = 0.f; int n = 0;
        for (int k = 0; k < KC; k++) { reg += s_reg[k]; n += s_prs[k]; }
        float nf = (float)n;
        float variance_term = var[b] / fmaxf(nf, 1.f);
        float npairs = nf * (nf - 1.f) * 0.5f;
        float distance_term = s_red[0] / fmaxf(npairs, 1.f);
        float reg_term = reg / fmaxf(nf, 1.f);
        float pb = variance_term + distance_term + 0.001f * reg_term;
        if (n == 0) pb = 0.f;
        atomicAdd(out, pb * 0.125f);           // / B
    }
}

extern "C" void kernel_launch(void* const* d_in, const int* in_sizes, int n_in,
                              void* d_out, int out_size, void* d_ws, size_t ws_size,
                              hipStream_t stream) {
    const float* emb = (const float*)d_in[0];
    const int*   lab = (const int*)d_in[1];
    float* out = (float*)d_out;

    const int B = 8;
    const int N = in_sizes[1] / B;             // 65536

    float* sums   = (float*)d_ws;
    float* counts = sums + (size_t)B * KE;
    float* var    = counts + (size_t)B * KC;

    int nf = B * KE + B * KC + B;
    k_init<<<(nf + 255) / 256, 256, 0, stream>>>(sums, nf, out);
    k_accum<<<B * BPB, 256, 0, stream>>>(emb, lab, sums, counts, N);
    k_hinge<<<B * BPB, 256, 0, stream>>>(emb, lab, sums, counts, var, N);
    k_final<<<B, 256, 0, stream>>>(sums, counts, var, out, B);
}

// Round 7
// 188.216 us; speedup vs baseline: 1.4343x; 1.0363x over previous
//
#include <hip/hip_runtime.h>
#include <math.h>
#include <stdint.h>

#define KC 33            // clusters
#define ED 32            // embedding dim
#define KE 1056          // KC*ED
#define CPAD 33          // padded stride for hinge center rows
#define BPB_A 128        // accum blocks per batch  -> chunk 512
#define TPA 128          // accum points per tile (16KB)
#define NSLOT 8          // half-waves per 256-thread block
#define BPB_H 256        // hinge blocks per batch  -> chunk 256 (1 pt/thread)

// ws layout (floats): sums[8*KE] | counts[8*KC] | var[8]

__global__ void k_init(float* __restrict__ ws, int nf, float* __restrict__ out) {
    int i = blockIdx.x * blockDim.x + threadIdx.x;
    if (i < nf) ws[i] = 0.f;
    if (i == 0) out[0] = 0.f;
}

// async global->LDS, 16B per lane, dest = wave-uniform base + lane*16
__device__ __forceinline__ void gload_lds16(const void* g, void* l) {
    __builtin_amdgcn_global_load_lds(
        (const __attribute__((address_space(1))) uint32_t*)g,
        (__attribute__((address_space(3))) uint32_t*)l, 16, 0, 0);
}

// stage one 16KB tile (128 pts x 128B): wave wv covers 4KB as 4x1KB instrs
__device__ __forceinline__ void stage_tile(const float* gbase, float* lbase,
                                           int wv, int ln) {
#pragma unroll
    for (int j = 0; j < 4; j++) {
        int off = wv * 4096 + j * 1024;   // bytes
        gload_lds16((const char*)gbase + off + ln * 16, (char*)lbase + off);
    }
}

// Pass 1: per-(b,k) sums. Async double-buffered global_load_lds staging into an
// UNPADDED point-major tile (bank = e for both wave halves: free). Half-wave
// per point, non-atomic RMW into per-half-wave private copies.
__global__ __launch_bounds__(256) void k_accum(const float* __restrict__ emb,
                                               const int* __restrict__ lab,
                                               float* __restrict__ sums,
                                               float* __restrict__ counts,
                                               int N) {
    __shared__ __align__(16) float s_tile[2][TPA * ED];  // 2 x 16KB
    __shared__ float s_priv[NSLOT * KE];                 // 33KB
    __shared__ int   s_lab[512];                         // chunk labels
    __shared__ float s_hist[KC];

    int t  = threadIdx.x;
    int wv = t >> 6, ln = t & 63;
    int e  = t & 31, slot = t >> 5;
    int b   = blockIdx.x / BPB_A;
    int blk = blockIdx.x % BPB_A;
    int chunk = N / BPB_A;                               // 512
    size_t pbase = (size_t)b * N + (size_t)blk * chunk;
    const int NT = chunk / TPA;                          // 4

    // issue async staging first: labels (wave 0, 2KB) + tile 0 (all waves)
    if (wv == 0) {
#pragma unroll
        for (int j = 0; j < 2; j++)
            gload_lds16(lab + pbase + j * 256 + ln * 4, (char*)s_lab + j * 1024);
    }
    stage_tile(emb + pbase * ED, s_tile[0], wv, ln);

    for (int i = t; i < NSLOT * KE; i += 256) s_priv[i] = 0.f;
    if (t < KC) s_hist[t] = 0.f;
    __syncthreads();   // vmcnt(0) drain: tile0 + labels resident; priv zeroed

    for (int tb = 0; tb < NT; tb++) {
        int cur = tb & 1;
        if (tb + 1 < NT)   // async prefetch next tile into other buffer
            stage_tile(emb + (pbase + (size_t)(tb + 1) * TPA) * ED,
                       s_tile[cur ^ 1], wv, ln);

        const float* tile = s_tile[cur];
        const int*   lp   = &s_lab[tb * TPA];
        float*       priv = &s_priv[slot * KE];
#pragma unroll
        for (int st = 0; st < TPA / NSLOT; st++) {
            int pt = st * NSLOT + slot;
            int k  = lp[pt];                  // 2 addrs/wave: broadcast, free
            priv[k * ED + e] += tile[pt * ED + e];   // bank=e both halves: free
        }
        __syncthreads();   // reads of cur done before it is restaged; prefetch drained
    }

    // histogram: 2 LDS atomics per thread (~8 wave-ops: cheap even at 220cyc/op)
    for (int i = t; i < chunk; i += 256) atomicAdd(&s_hist[s_lab[i]], 1.f);
    __syncthreads();

    for (int i = t; i < KE; i += 256) {
        float v = 0.f;
#pragma unroll
        for (int s = 0; s < NSLOT; s++) v += s_priv[s * KE + i];
        atomicAdd(&sums[(size_t)b * KE + i], v);
    }
    if (t < KC) atomicAdd(&counts[b * KC + t], s_hist[t]);
}

// Pass 2: thread-owns-point hinge, 1 point/thread, 2048 blocks (~full occupancy).
// Center reads are one ds_read per j serving all 64 lane-points (0.5 DS/pt).
__global__ __launch_bounds__(256) void k_hinge(const float* __restrict__ emb,
                                               const int* __restrict__ lab,
                                               const float* __restrict__ sums,
                                               const float* __restrict__ counts,
                                               float* __restrict__ var, int N) {
    __shared__ float s_ctr[KC * CPAD];
    __shared__ float s_inv[KC];
    __shared__ float s_red[4];
    int t = threadIdx.x;
    int b   = blockIdx.x / BPB_H;
    int blk = blockIdx.x % BPB_H;
    size_t pbase = (size_t)b * N + (size_t)blk * 256;

    // issue own point load first; center-table setup hides the latency
    const float4* g4 = (const float4*)(emb + (pbase + t) * ED);
    float4 A0 = g4[0], A1 = g4[1], A2 = g4[2], A3 = g4[3];
    float4 A4 = g4[4], A5 = g4[5], A6 = g4[6], A7 = g4[7];
    int ka = lab[pbase + t];

    if (t < KC) {
        float c = counts[b * KC + t];
        s_inv[t] = (t > 0 && c > 0.f) ? 1.f / fmaxf(c, 1.f) : 0.f;
    }
    for (int i = t; i < KE; i += 256) {
        int k = i >> 5, j = i & 31;
        s_ctr[k * CPAD + j] = sums[(size_t)b * KE + i] / fmaxf(counts[b * KC + k], 1.f);
    }
    __syncthreads();

    float x[32];
    *(float4*)(x +  0) = A0; *(float4*)(x +  4) = A1;
    *(float4*)(x +  8) = A2; *(float4*)(x + 12) = A3;
    *(float4*)(x + 16) = A4; *(float4*)(x + 20) = A5;
    *(float4*)(x + 24) = A6; *(float4*)(x + 28) = A7;

    const float* cr = &s_ctr[ka * CPAD];
    float d2 = 0.f;
#pragma unroll
    for (int j = 0; j < ED; j++) {
        float d = x[j] - cr[j];
        d2 = fmaf(d, d, d2);
    }
    float dist = sqrtf(fmaxf(d2, 1e-12f));
    float hs = fmaxf(dist - 0.5f, 0.f) * s_inv[ka];

    hs += __shfl_xor(hs, 1);  hs += __shfl_xor(hs, 2);  hs += __shfl_xor(hs, 4);
    hs += __shfl_xor(hs, 8);  hs += __shfl_xor(hs, 16); hs += __shfl_xor(hs, 32);
    if ((t & 63) == 0) s_red[t >> 6] = hs;
    __syncthreads();
    if (t == 0)
        atomicAdd(&var[b], s_red[0] + s_red[1] + s_red[2] + s_red[3]);
}

// Epilogue: one block per batch; recompute centers from sums/counts.
__global__ __launch_bounds__(256) void k_final(const float* __restrict__ sums,
                                               const float* __restrict__ counts,
                                               const float* __restrict__ var,
                                               float* __restrict__ out, int B) {
    __shared__ float s_ctr[KE];
    __shared__ float s_cnt[KC];
    __shared__ float s_reg[KC];
    __shared__ int   s_prs[KC];
    __shared__ float s_red[256];
    int b = blockIdx.x;
    int t = threadIdx.x;

    if (t < KC) {
        float c = counts[b * KC + t];
        s_cnt[t] = fmaxf(c, 1.f);
        s_prs[t] = (t > 0 && c > 0.f) ? 1 : 0;
    }
    __syncthreads();
    for (int i = t; i < KE; i += 256)
        s_ctr[i] = sums[(size_t)b * KE + i] / s_cnt[i >> 5];
    __syncthreads();
    if (t < KC) {
        float n2 = 0.f;
        for (int e2 = 0; e2 < ED; e2++) { float c = s_ctr[t * ED + e2]; n2 += c * c; }
        s_reg[t] = s_prs[t] ? sqrtf(fmaxf(n2, 1e-12f)) : 0.f;
    }
    __syncthreads();

    float psum = 0.f;
    for (int q = t; q < KC * KC; q += 256) {
        int i = q / KC, j = q % KC;
        if (i < j && s_prs[i] && s_prs[j]) {
            float d2 = 0.f;
            for (int e2 = 0; e2 < ED; e2++) {
                float d = s_ctr[i * ED + e2] - s_ctr[j * ED + e2];
                d2 += d * d;
            }
            float cd = sqrtf(fmaxf(d2, 1e-12f));
            psum += fmaxf(3.0f - cd, 0.f);     // 2*DELTA_D = 3.0
        }
    }
    s_red[t] = psum;
    __syncthreads();
    for (int s = 128; s > 0; s >>= 1) {
        if (t < s) s_red[t] += s_red[t + s];
        __syncthreads();
    }

    if (t == 0) {
        float reg = 0.f; int n = 0;
        for (int k = 0; k < KC; k++) { reg += s_reg[k]; n += s_prs[k]; }
        float nf = (float)n;
        float variance_term = var[b] / fmaxf(nf, 1.f);
        float npairs = nf * (nf - 1.f) * 0.5f;
        float distance_term = s_red[0] / fmaxf(npairs, 1.f);
        float reg_term = reg / fmaxf(nf, 1.f);
        float pb = variance_term + distance_term + 0.001f * reg_term;
        if (n == 0) pb = 0.f;
        atomicAdd(out, pb * 0.125f);           // / B
    }
}

extern "C" void kernel_launch(void* const* d_in, const int* in_sizes, int n_in,
                              void* d_out, int out_size, void* d_ws, size_t ws_size,
                              hipStream_t stream) {
    const float* emb = (const float*)d_in[0];
    const int*   lab = (const int*)d_in[1];
    float* out = (float*)d_out;

    const int B = 8;
    const int N = in_sizes[1] / B;             // 65536

    float* sums   = (float*)d_ws;
    float* counts = sums + (size_t)B * KE;
    float* var    = counts + (size_t)B * KC;

    int nf = B * KE + B * KC + B;
    k_init<<<(nf + 255) / 256, 256, 0, stream>>>(sums, nf, out);
    k_accum<<<B * BPB_A, 256, 0, stream>>>(emb, lab, sums, counts, N);
    k_hinge<<<B * BPB_H, 256, 0, stream>>>(emb, lab, sums, counts, var, N);
    k_final<<<B, 256, 0, stream>>>(sums, counts, var, out, B);
}

// Round 8
// 135.454 us; speedup vs baseline: 1.9930x; 1.3895x over previous
//
#include <hip/hip_runtime.h>
#include <math.h>
#include <stdint.h>

#define KC 33            // clusters
#define ED 32            // embedding dim
#define KE 1056          // KC*ED
#define PAD 33           // padded leading dim for hinge point tile
#define CPAD 33          // padded stride for hinge center rows
#define BPB_A 128        // accum blocks per batch  -> chunk 512
#define TPA 128          // accum points per tile (16KB)
#define NSLOT 8          // half-waves per 256-thread block
#define BPB_H 128        // hinge blocks per batch  -> chunk 512
#define TPH 256          // hinge points per staged tile (1 per thread)

// ws layout (floats): sums[8*KE] | counts[8*KC] | var[8] | ctr[8*KE] | inv[8*KC]

__global__ void k_init(float* __restrict__ ws, int nf, float* __restrict__ out) {
    int i = blockIdx.x * blockDim.x + threadIdx.x;
    if (i < nf) ws[i] = 0.f;
    if (i == 0) out[0] = 0.f;
}

// async global->LDS, 16B per lane, dest = wave-uniform base + lane*16
__device__ __forceinline__ void gload_lds16(const void* g, void* l) {
    __builtin_amdgcn_global_load_lds(
        (const __attribute__((address_space(1))) uint32_t*)g,
        (__attribute__((address_space(3))) uint32_t*)l, 16, 0, 0);
}

// stage one 16KB tile (128 pts x 128B): wave wv covers 4KB as 4x1KB instrs
__device__ __forceinline__ void stage_tile(const float* gbase, float* lbase,
                                           int wv, int ln) {
#pragma unroll
    for (int j = 0; j < 4; j++) {
        int off = wv * 4096 + j * 1024;   // bytes
        gload_lds16((const char*)gbase + off + ln * 16, (char*)lbase + off);
    }
}

// Pass 1 (proven in R7): async double-buffered global_load_lds staging into an
// UNPADDED point-major tile (bank = e for both wave halves: free). Half-wave
// per point, non-atomic RMW into per-half-wave private copies.
__global__ __launch_bounds__(256) void k_accum(const float* __restrict__ emb,
                                               const int* __restrict__ lab,
                                               float* __restrict__ sums,
                                               float* __restrict__ counts,
                                               int N) {
    __shared__ __align__(16) float s_tile[2][TPA * ED];  // 2 x 16KB
    __shared__ float s_priv[NSLOT * KE];                 // 33KB
    __shared__ int   s_lab[512];                         // chunk labels
    __shared__ float s_hist[KC];

    int t  = threadIdx.x;
    int wv = t >> 6, ln = t & 63;
    int e  = t & 31, slot = t >> 5;
    int b   = blockIdx.x / BPB_A;
    int blk = blockIdx.x % BPB_A;
    int chunk = N / BPB_A;                               // 512
    size_t pbase = (size_t)b * N + (size_t)blk * chunk;
    const int NT = chunk / TPA;                          // 4

    // issue async staging first: labels (wave 0, 2KB) + tile 0 (all waves)
    if (wv == 0) {
#pragma unroll
        for (int j = 0; j < 2; j++)
            gload_lds16(lab + pbase + j * 256 + ln * 4, (char*)s_lab + j * 1024);
    }
    stage_tile(emb + pbase * ED, s_tile[0], wv, ln);

    for (int i = t; i < NSLOT * KE; i += 256) s_priv[i] = 0.f;
    if (t < KC) s_hist[t] = 0.f;
    __syncthreads();   // vmcnt(0) drain: tile0 + labels resident; priv zeroed

    for (int tb = 0; tb < NT; tb++) {
        int cur = tb & 1;
        if (tb + 1 < NT)   // async prefetch next tile into other buffer
            stage_tile(emb + (pbase + (size_t)(tb + 1) * TPA) * ED,
                       s_tile[cur ^ 1], wv, ln);

        const float* tile = s_tile[cur];
        const int*   lp   = &s_lab[tb * TPA];
        float*       priv = &s_priv[slot * KE];
#pragma unroll
        for (int st = 0; st < TPA / NSLOT; st++) {
            int pt = st * NSLOT + slot;
            int k  = lp[pt];                  // 2 addrs/wave: broadcast, free
            priv[k * ED + e] += tile[pt * ED + e];   // bank=e both halves: free
        }
        __syncthreads();   // reads of cur done before restage; prefetch drained
    }

    // histogram: 2 LDS atomics per thread
    for (int i = t; i < chunk; i += 256) atomicAdd(&s_hist[s_lab[i]], 1.f);
    __syncthreads();

    for (int i = t; i < KE; i += 256) {
        float v = 0.f;
#pragma unroll
        for (int s = 0; s < NSLOT; s++) v += s_priv[s * KE + i];
        atomicAdd(&sums[(size_t)b * KE + i], v);
    }
    if (t < KC) atomicAdd(&counts[b * KC + t], s_hist[t]);
}

// Tiny: centers + inv from sums/counts (runs once; removes divides/gathers
// from the 1024 hinge blocks).
__global__ void k_centers(const float* __restrict__ sums,
                          const float* __restrict__ counts,
                          float* __restrict__ ctr, float* __restrict__ inv, int B) {
    int i = blockIdx.x * blockDim.x + threadIdx.x;
    if (i < B * KE)
        ctr[i] = sums[i] / fmaxf(counts[i >> 5], 1.0f);   // i>>5 = b*KC+k
    if (i < B * KC) {
        int k = i % KC;
        float c = counts[i];
        inv[i] = (k > 0 && c > 0.f) ? 1.f / fmaxf(c, 1.f) : 0.f;
    }
}

// Pass 2 (R4-proven structure): register-prefetch staged padded LDS tile,
// thread-owns-point-within-tile. var[b] += sum_p max(||x-c||-0.5,0)*inv[k_p].
__global__ __launch_bounds__(256) void k_hinge(const float* __restrict__ emb,
                                               const int* __restrict__ lab,
                                               const float* __restrict__ ctr,
                                               const float* __restrict__ inv,
                                               float* __restrict__ var, int N) {
    __shared__ float s_tile[TPH * PAD];      // 33.8 KB
    __shared__ float s_ctr[KC * CPAD];       // 4.3 KB
    __shared__ float s_inv[KC];
    __shared__ int   s_lab[TPH];
    __shared__ float s_red[4];
    int t     = threadIdx.x;
    int b     = blockIdx.x / BPB_H;
    int blk   = blockIdx.x % BPB_H;
    int chunk = N / BPB_H;                   // 512
    size_t pbase = (size_t)b * N + (size_t)blk * chunk;
    const int NT = chunk / TPH;              // 2

    // prefetch tile 0 (8 float4 per thread = 1 point per thread)
    const float4* g4 = (const float4*)(emb + pbase * ED);
    float4 r0 = g4[t],        r1 = g4[t + 256],  r2 = g4[t + 512],  r3 = g4[t + 768];
    float4 r4 = g4[t + 1024], r5 = g4[t + 1280], r6 = g4[t + 1536], r7 = g4[t + 1792];
    int rl = lab[pbase + t];

    // coalesced center/inv table setup (precomputed by k_centers)
    if (t < KC) s_inv[t] = inv[b * KC + t];
    for (int i = t; i < KE; i += 256) {
        int k = i >> 5, j = i & 31;
        s_ctr[k * CPAD + j] = ctr[(size_t)b * KE + i];
    }

    float hs = 0.f;
    for (int tb = 0; tb < NT; tb++) {
        {   // unpack staged registers into padded tile
            int f, p, m;
            f = t;         p = f >> 3; m = (f & 7) * 4;
            { float* d = &s_tile[PAD * p + m]; d[0]=r0.x; d[1]=r0.y; d[2]=r0.z; d[3]=r0.w; }
            f = t + 256;   p = f >> 3; m = (f & 7) * 4;
            { float* d = &s_tile[PAD * p + m]; d[0]=r1.x; d[1]=r1.y; d[2]=r1.z; d[3]=r1.w; }
            f = t + 512;   p = f >> 3; m = (f & 7) * 4;
            { float* d = &s_tile[PAD * p + m]; d[0]=r2.x; d[1]=r2.y; d[2]=r2.z; d[3]=r2.w; }
            f = t + 768;   p = f >> 3; m = (f & 7) * 4;
            { float* d = &s_tile[PAD * p + m]; d[0]=r3.x; d[1]=r3.y; d[2]=r3.z; d[3]=r3.w; }
            f = t + 1024;  p = f >> 3; m = (f & 7) * 4;
            { float* d = &s_tile[PAD * p + m]; d[0]=r4.x; d[1]=r4.y; d[2]=r4.z; d[3]=r4.w; }
            f = t + 1280;  p = f >> 3; m = (f & 7) * 4;
            { float* d = &s_tile[PAD * p + m]; d[0]=r5.x; d[1]=r5.y; d[2]=r5.z; d[3]=r5.w; }
            f = t + 1536;  p = f >> 3; m = (f & 7) * 4;
            { float* d = &s_tile[PAD * p + m]; d[0]=r6.x; d[1]=r6.y; d[2]=r6.z; d[3]=r6.w; }
            f = t + 1792;  p = f >> 3; m = (f & 7) * 4;
            { float* d = &s_tile[PAD * p + m]; d[0]=r7.x; d[1]=r7.y; d[2]=r7.z; d[3]=r7.w; }
        }
        s_lab[t] = rl;
        __syncthreads();                     // also covers s_ctr/s_inv (tb==0)

        if (tb + 1 < NT) {                   // prefetch next tile during compute
            const float4* gn = (const float4*)(emb + (pbase + (size_t)(tb + 1) * TPH) * ED);
            r0 = gn[t];        r1 = gn[t + 256];  r2 = gn[t + 512];  r3 = gn[t + 768];
            r4 = gn[t + 1024]; r5 = gn[t + 1280]; r6 = gn[t + 1536]; r7 = gn[t + 1792];
            rl = lab[pbase + (size_t)(tb + 1) * TPH + t];
        }

        int   k  = s_lab[t];
        float iv = s_inv[k];
        const float* xr = &s_tile[t * PAD];      // bank (t+j)%32: 2-way = free
        const float* cr = &s_ctr[k * CPAD];      // birthday gather ~2x
        float d2 = 0.f;
#pragma unroll
        for (int j = 0; j < ED; j++) {
            float d = xr[j] - cr[j];
            d2 = fmaf(d, d, d2);
        }
        float dist = sqrtf(fmaxf(d2, 1e-12f));
        hs += fmaxf(dist - 0.5f, 0.f) * iv;
        __syncthreads();
    }

    hs += __shfl_xor(hs, 1);  hs += __shfl_xor(hs, 2);  hs += __shfl_xor(hs, 4);
    hs += __shfl_xor(hs, 8);  hs += __shfl_xor(hs, 16); hs += __shfl_xor(hs, 32);
    if ((t & 63) == 0) s_red[t >> 6] = hs;
    __syncthreads();
    if (t == 0)
        atomicAdd(&var[b], s_red[0] + s_red[1] + s_red[2] + s_red[3]);
}

// Epilogue: one block per batch; recompute centers from sums/counts.
__global__ __launch_bounds__(256) void k_final(const float* __restrict__ sums,
                                               const float* __restrict__ counts,
                                               const float* __restrict__ var,
                                               float* __restrict__ out, int B) {
    __shared__ float s_ctr[KE];
    __shared__ float s_cnt[KC];
    __shared__ float s_reg[KC];
    __shared__ int   s_prs[KC];
    __shared__ float s_red[256];
    int b = blockIdx.x;
    int t = threadIdx.x;

    if (t < KC) {
        float c = counts[b * KC + t];
        s_cnt[t] = fmaxf(c, 1.f);
        s_prs[t] = (t > 0 && c > 0.f) ? 1 : 0;
    }
    __syncthreads();
    for (int i = t; i < KE; i += 256)
        s_ctr[i] = sums[(size_t)b * KE + i] / s_cnt[i >> 5];
    __syncthreads();
    if (t < KC) {
        float n2 = 0.f;
        for (int e2 = 0; e2 < ED; e2++) { float c = s_ctr[t * ED + e2]; n2 += c * c; }
        s_reg[t] = s_prs[t] ? sqrtf(fmaxf(n2, 1e-12f)) : 0.f;
    }
    __syncthreads();

    float psum = 0.f;
    for (int q = t; q < KC * KC; q += 256) {
        int i = q / KC, j = q % KC;
        if (i < j && s_prs[i] && s_prs[j]) {
            float d2 = 0.f;
            for (int e2 = 0; e2 < ED; e2++) {
                float d = s_ctr[i * ED + e2] - s_ctr[j * ED + e2];
                d2 += d * d;
            }
            float cd = sqrtf(fmaxf(d2, 1e-12f));
            psum += fmaxf(3.0f - cd, 0.f);     // 2*DELTA_D = 3.0
        }
    }
    s_red[t] = psum;
    __syncthreads();
    for (int s = 128; s > 0; s >>= 1) {
        if (t < s) s_red[t] += s_red[t + s];
        __syncthreads();
    }

    if (t == 0) {
        float reg = 0.f; int n = 0;
        for (int k = 0; k < KC; k++) { reg += s_reg[k]; n += s_prs[k]; }
        float nf = (float)n;
        float variance_term = var[b] / fmaxf(nf, 1.f);
        float npairs = nf * (nf - 1.f) * 0.5f;
        float distance_term = s_red[0] / fmaxf(npairs, 1.f);
        float reg_term = reg / fmaxf(nf, 1.f);
        float pb = variance_term + distance_term + 0.001f * reg_term;
        if (n == 0) pb = 0.f;
        atomicAdd(out, pb * 0.125f);           // / B
    }
}

extern "C" void kernel_launch(void* const* d_in, const int* in_sizes, int n_in,
                              void* d_out, int out_size, void* d_ws, size_t ws_size,
                              hipStream_t stream) {
    const float* emb = (const float*)d_in[0];
    const int*   lab = (const int*)d_in[1];
    float* out = (float*)d_out;

    const int B = 8;
    const int N = in_sizes[1] / B;             // 65536

    float* sums   = (float*)d_ws;
    float* counts = sums + (size_t)B * KE;
    float* var    = counts + (size_t)B * KC;
    float* ctr    = var + B;
    float* inv    = ctr + (size_t)B * KE;

    int nf = B * KE + B * KC + B;              // zero sums/counts/var
    k_init<<<(nf + 255) / 256, 256, 0, stream>>>(sums, nf, out);
    k_accum<<<B * BPB_A, 256, 0, stream>>>(emb, lab, sums, counts, N);
    k_centers<<<(B * KE + 255) / 256, 256, 0, stream>>>(sums, counts, ctr, inv, B);
    k_hinge<<<B * BPB_H, 256, 0, stream>>>(emb, lab, ctr, inv, var, N);
    k_final<<<B, 256, 0, stream>>>(sums, counts, var, out, B);
}

// Round 9
// 134.810 us; speedup vs baseline: 2.0026x; 1.0048x over previous
//
#include <hip/hip_runtime.h>
#include <math.h>
#include <stdint.h>

#define KC 33            // clusters
#define ED 32            // embedding dim
#define KE 1056          // KC*ED
#define BPB_A 128        // accum blocks per batch  -> chunk 512
#define TPA 128          // accum points per tile (16KB)
#define NSLOT 8          // half-waves per 256-thread block
#define BPB_H 128        // hinge blocks per batch  -> chunk 512
#define TPH 256          // hinge points per tile (32KB, 1 pt/thread)

// ws layout (floats): sums[8*KE] | counts[8*KC] | var[8]

__global__ void k_init(float* __restrict__ ws, int nf, float* __restrict__ out) {
    int i = blockIdx.x * blockDim.x + threadIdx.x;
    if (i < nf) ws[i] = 0.f;
    if (i == 0) out[0] = 0.f;
}

// async global->LDS, 16B per lane, dest = wave-uniform base + lane*16
__device__ __forceinline__ void gload_lds16(const void* g, void* l) {
    __builtin_amdgcn_global_load_lds(
        (const __attribute__((address_space(1))) uint32_t*)g,
        (__attribute__((address_space(3))) uint32_t*)l, 16, 0, 0);
}

// stage a 16KB tile: wave wv covers 4KB as 4x1KB instrs
__device__ __forceinline__ void stage_tile16k(const float* gbase, float* lbase,
                                              int wv, int ln) {
#pragma unroll
    for (int j = 0; j < 4; j++) {
        int off = wv * 4096 + j * 1024;
        gload_lds16((const char*)gbase + off + ln * 16, (char*)lbase + off);
    }
}

// stage a 32KB tile: wave wv covers 8KB as 8x1KB instrs
__device__ __forceinline__ void stage_tile32k(const float* gbase, float* lbase,
                                              int wv, int ln) {
#pragma unroll
    for (int j = 0; j < 8; j++) {
        int off = wv * 8192 + j * 1024;
        gload_lds16((const char*)gbase + off + ln * 16, (char*)lbase + off);
    }
}

// Pass 1 (proven): async double-buffered global_load_lds staging, unpadded
// point-major tile (bank=e both halves: free). Half-wave per point, non-atomic
// RMW into per-half-wave private copies.
__global__ __launch_bounds__(256) void k_accum(const float* __restrict__ emb,
                                               const int* __restrict__ lab,
                                               float* __restrict__ sums,
                                               float* __restrict__ counts,
                                               int N) {
    __shared__ __align__(16) float s_tile[2][TPA * ED];  // 2 x 16KB
    __shared__ float s_priv[NSLOT * KE];                 // 33KB
    __shared__ int   s_lab[512];
    __shared__ float s_hist[KC];

    int t  = threadIdx.x;
    int wv = t >> 6, ln = t & 63;
    int e  = t & 31, slot = t >> 5;
    int b   = blockIdx.x / BPB_A;
    int blk = blockIdx.x % BPB_A;
    int chunk = N / BPB_A;                               // 512
    size_t pbase = (size_t)b * N + (size_t)blk * chunk;
    const int NT = chunk / TPA;                          // 4

    if (wv == 0) {
#pragma unroll
        for (int j = 0; j < 2; j++)
            gload_lds16(lab + pbase + j * 256 + ln * 4, (char*)s_lab + j * 1024);
    }
    stage_tile16k(emb + pbase * ED, s_tile[0], wv, ln);

    for (int i = t; i < NSLOT * KE; i += 256) s_priv[i] = 0.f;
    if (t < KC) s_hist[t] = 0.f;
    __syncthreads();   // vmcnt drain: tile0 + labels resident; priv zeroed

    for (int tb = 0; tb < NT; tb++) {
        int cur = tb & 1;
        if (tb + 1 < NT)
            stage_tile16k(emb + (pbase + (size_t)(tb + 1) * TPA) * ED,
                          s_tile[cur ^ 1], wv, ln);

        const float* tile = s_tile[cur];
        const int*   lp   = &s_lab[tb * TPA];
        float*       priv = &s_priv[slot * KE];
#pragma unroll
        for (int st = 0; st < TPA / NSLOT; st++) {
            int pt = st * NSLOT + slot;
            int k  = lp[pt];
            priv[k * ED + e] += tile[pt * ED + e];
        }
        __syncthreads();
    }

    for (int i = t; i < chunk; i += 256) atomicAdd(&s_hist[s_lab[i]], 1.f);
    __syncthreads();

    for (int i = t; i < KE; i += 256) {
        float v = 0.f;
#pragma unroll
        for (int s = 0; s < NSLOT; s++) v += s_priv[s * KE + i];
        atomicAdd(&sums[(size_t)b * KE + i], v);
    }
    if (t < KC) atomicAdd(&counts[b * KC + t], s_hist[t]);
}

// Pass 2: async double-buffered unpadded staging; thread-owns-point with
// ROTATED reads idx=(j+t)&31 -> bank (j+t)&31 for both the point row and the
// center row: conflict-free for any label. Centers computed in-block from
// sums/counts during tile-0 flight (k_centers fused away).
__global__ __launch_bounds__(256) void k_hinge(const float* __restrict__ emb,
                                               const int* __restrict__ lab,
                                               const float* __restrict__ sums,
                                               const float* __restrict__ counts,
                                               float* __restrict__ var, int N) {
    __shared__ __align__(16) float s_tile[2][TPH * ED];  // 2 x 32KB
    __shared__ float s_ctr[KE];                          // unpadded
    __shared__ float s_inv[KC];
    __shared__ int   s_lab[512];
    __shared__ float s_red[4];

    int t  = threadIdx.x;
    int wv = t >> 6, ln = t & 63;
    int b   = blockIdx.x / BPB_H;
    int blk = blockIdx.x % BPB_H;
    int chunk = N / BPB_H;                               // 512
    size_t pbase = (size_t)b * N + (size_t)blk * chunk;
    const int NT = chunk / TPH;                          // 2

    if (wv == 0) {
#pragma unroll
        for (int j = 0; j < 2; j++)
            gload_lds16(lab + pbase + j * 256 + ln * 4, (char*)s_lab + j * 1024);
    }
    stage_tile32k(emb + pbase * ED, s_tile[0], wv, ln);

    // center table from sums/counts while tile 0 is in flight
    if (t < KC) {
        float c = counts[b * KC + t];
        s_inv[t] = (t > 0 && c > 0.f) ? 1.f / fmaxf(c, 1.f) : 0.f;
    }
    for (int i = t; i < KE; i += 256)
        s_ctr[i] = sums[(size_t)b * KE + i] / fmaxf(counts[b * KC + (i >> 5)], 1.f);
    __syncthreads();   // drains staging; ctr/inv visible

    float hs = 0.f;
    for (int tb = 0; tb < NT; tb++) {
        int cur = tb & 1;
        if (tb + 1 < NT)
            stage_tile32k(emb + (pbase + (size_t)(tb + 1) * TPH) * ED,
                          s_tile[cur ^ 1], wv, ln);

        int k = s_lab[tb * TPH + t];
        const float* xr = &s_tile[cur][t * ED];
        const float* cr = &s_ctr[k * ED];
        float d2 = 0.f;
#pragma unroll
        for (int j = 0; j < ED; j++) {
            int idx = (j + t) & 31;          // rotation: bank=(j+t)&31, conflict-free
            float d = xr[idx] - cr[idx];
            d2 = fmaf(d, d, d2);
        }
        float dist = sqrtf(fmaxf(d2, 1e-12f));
        hs += fmaxf(dist - 0.5f, 0.f) * s_inv[k];
        __syncthreads();
    }

    hs += __shfl_xor(hs, 1);  hs += __shfl_xor(hs, 2);  hs += __shfl_xor(hs, 4);
    hs += __shfl_xor(hs, 8);  hs += __shfl_xor(hs, 16); hs += __shfl_xor(hs, 32);
    if ((t & 63) == 0) s_red[t >> 6] = hs;
    __syncthreads();
    if (t == 0)
        atomicAdd(&var[b], s_red[0] + s_red[1] + s_red[2] + s_red[3]);
}

// Epilogue: one block per batch; recompute centers from sums/counts.
__global__ __launch_bounds__(256) void k_final(const float* __restrict__ sums,
                                               const float* __restrict__ counts,
                                               const float* __restrict__ var,
                                               float* __restrict__ out, int B) {
    __shared__ float s_ctr[KE];
    __shared__ float s_cnt[KC];
    __shared__ float s_reg[KC];
    __shared__ int   s_prs[KC];
    __shared__ float s_red[256];
    int b = blockIdx.x;
    int t = threadIdx.x;

    if (t < KC) {
        float c = counts[b * KC + t];
        s_cnt[t] = fmaxf(c, 1.f);
        s_prs[t] = (t > 0 && c > 0.f) ? 1 : 0;
    }
    __syncthreads();
    for (int i = t; i < KE; i += 256)
        s_ctr[i] = sums[(size_t)b * KE + i] / s_cnt[i >> 5];
    __syncthreads();
    if (t < KC) {
        float n2 = 0.f;
        for (int e2 = 0; e2 < ED; e2++) { float c = s_ctr[t * ED + e2]; n2 += c * c; }
        s_reg[t] = s_prs[t] ? sqrtf(fmaxf(n2, 1e-12f)) : 0.f;
    }
    __syncthreads();

    float psum = 0.f;
    for (int q = t; q < KC * KC; q += 256) {
        int i = q / KC, j = q % KC;
        if (i < j && s_prs[i] && s_prs[j]) {
            float d2 = 0.f;
            for (int e2 = 0; e2 < ED; e2++) {
                float d = s_ctr[i * ED + e2] - s_ctr[j * ED + e2];
                d2 += d * d;
            }
            float cd = sqrtf(fmaxf(d2, 1e-12f));
            psum += fmaxf(3.0f - cd, 0.f);     // 2*DELTA_D = 3.0
        }
    }
    s_red[t] = psum;
    __syncthreads();
    for (int s = 128; s > 0; s >>= 1) {
        if (t < s) s_red[t] += s_red[t + s];
        __syncthreads();
    }

    if (t == 0) {
        float reg = 0.f; int n = 0;
        for (int k = 0; k < KC; k++) { reg += s_reg[k]; n += s_prs[k]; }
        float nf = (float)n;
        float variance_term = var[b] / fmaxf(nf, 1.f);
        float npairs = nf * (nf - 1.f) * 0.5f;
        float distance_term = s_red[0] / fmaxf(npairs, 1.f);
        float reg_term = reg / fmaxf(nf, 1.f);
        float pb = variance_term + distance_term + 0.001f * reg_term;
        if (n == 0) pb = 0.f;
        atomicAdd(out, pb * 0.125f);           // / B
    }
}

extern "C" void kernel_launch(void* const* d_in, const int* in_sizes, int n_in,
                              void* d_out, int out_size, void* d_ws, size_t ws_size,
                              hipStream_t stream) {
    const float* emb = (const float*)d_in[0];
    const int*   lab = (const int*)d_in[1];
    float* out = (float*)d_out;

    const int B = 8;
    const int N = in_sizes[1] / B;             // 65536

    float* sums   = (float*)d_ws;
    float* counts = sums + (size_t)B * KE;
    float* var    = counts + (size_t)B * KC;

    int nf = B * KE + B * KC + B;              // zero sums/counts/var
    k_init<<<(nf + 255) / 256, 256, 0, stream>>>(sums, nf, out);
    k_accum<<<B * BPB_A, 256, 0, stream>>>(emb, lab, sums, counts, N);
    k_hinge<<<B * BPB_H, 256, 0, stream>>>(emb, lab, sums, counts, var, N);
    k_final<<<B, 256, 0, stream>>>(sums, counts, var, out, B);
}